// Round 7
// baseline (2230.939 us; speedup 1.0000x reference)
//
#include <hip/hip_runtime.h>
#include <hip/hip_bf16.h>

#define VOCAB 50000
#define EDIM 256
#define HDIM 256
#define BATCH 64
#define SEQ 2048

// group stride in floats for padded h storage: 32 cols + 4 pad -> banks rotate by 4 per group
#define GSTRIDE 36

// ---------------- kernel 0: transpose W_ih (H x E) -> W_T (E x H) -------------
__global__ void k_transpose(const float* __restrict__ W, float* __restrict__ WT) {
    int idx = blockIdx.x * 256 + threadIdx.x;
    int e = idx >> 8;
    int i = idx & 255;
    WT[idx] = W[i * 256 + e];
}

// ---------------- kernel 1: P[v][i] = sum_e emb[v][e] * W_ih[i][e] ------------
__global__ __launch_bounds__(256) void k_project(const float* __restrict__ emb,
                                                 const float* __restrict__ WT,
                                                 float* __restrict__ P) {
    __shared__ float etile[32 * 256];
    const int v0 = blockIdx.x * 32;
    const int tid = threadIdx.x;

    #pragma unroll 4
    for (int k = 0; k < 32; ++k) {
        int v = v0 + k;
        etile[k * 256 + tid] = (v < VOCAB) ? emb[(size_t)v * 256 + tid] : 0.0f;
    }
    __syncthreads();

    float acc[32];
    #pragma unroll
    for (int k = 0; k < 32; ++k) acc[k] = 0.0f;

    for (int e0 = 0; e0 < 256; e0 += 4) {
        float w0 = WT[(size_t)(e0 + 0) * 256 + tid];
        float w1 = WT[(size_t)(e0 + 1) * 256 + tid];
        float w2 = WT[(size_t)(e0 + 2) * 256 + tid];
        float w3 = WT[(size_t)(e0 + 3) * 256 + tid];
        #pragma unroll
        for (int k = 0; k < 32; ++k) {
            float4 ev = *(const float4*)&etile[k * 256 + e0];
            acc[k] = fmaf(ev.x, w0, acc[k]);
            acc[k] = fmaf(ev.y, w1, acc[k]);
            acc[k] = fmaf(ev.z, w2, acc[k]);
            acc[k] = fmaf(ev.w, w3, acc[k]);
        }
    }
    #pragma unroll 4
    for (int k = 0; k < 32; ++k) {
        int v = v0 + k;
        if (v < VOCAB) P[(size_t)v * 256 + tid] = acc[k];
    }
}

// ---------------- kernel 2: recurrence -----------------------------------------
// 512 threads = 8 waves. Wave w owns output rows 32w..32w+31.
// Lane l: rows 32w+4*(l&7)+{0..3}, cols 32*(l>>3)..+31 -> 128 weight regs
// (unified VGPR/AGPR file; VALU reads AGPRs directly, so demotion is free).
// Per step: 8 broadcast ds_read_b128 of h (bank-rotated groups), 128 FMAs,
// shfl_xor(8,16,32) butterfly (partials of a row live in ONE wave),
// lanes 0..7 finalize (xp + tanh) and write 32 rows via one ds_write_b128.
// Double-buffered h -> ONE __syncthreads per step.
__device__ __forceinline__ float tanh_fast(float x) {
    float ax = fabsf(x);
    float e  = __expf(-2.0f * ax);
    float r  = (1.0f - e) / (1.0f + e);
    return copysignf(r, x);
}

__global__ __launch_bounds__(512, 2) void k_rnn(const int* __restrict__ tokens,
                                                const int* __restrict__ lengths,
                                                const float* __restrict__ P,
                                                const float* __restrict__ Whh,
                                                const float* __restrict__ Wcls,
                                                const float* __restrict__ bcls,
                                                float* __restrict__ out) {
    __shared__ float hbuf[2][8 * GSTRIDE];   // padded: group c at c*GSTRIDE, 32 valid + 4 pad
    __shared__ int   tok_lds[SEQ];

    const int b   = blockIdx.x;
    const int tid = threadIdx.x;
    const int len = lengths[b];

    #pragma unroll
    for (int k = 0; k < 4; ++k)
        tok_lds[tid + k * 512] = tokens[b * SEQ + tid + k * 512];
    if (tid < 8 * GSTRIDE) hbuf[0][tid] = 0.0f;

    const int w    = tid >> 6;          // wave id 0..7 (row block)
    const int l    = tid & 63;          // lane
    const int k8   = l & 7;             // row sub-group within wave
    const int cgrp = l >> 3;            // col group 0..7
    const int row0 = 32 * w + 4 * k8;   // this lane's 4 rows

    // ---- weights -> 128 regs ----
    float4 wv[4][8];
    #pragma unroll
    for (int j = 0; j < 4; ++j) {
        const float4* src = (const float4*)(Whh + (size_t)(row0 + j) * 256 + 32 * cgrp);
        #pragma unroll
        for (int m = 0; m < 8; ++m) wv[j][m] = src[m];
    }
    __syncthreads();

    // xp prefetch: finalize lanes are l<8 (then cgrp==0, row0 == 32w+4l)
    const bool fin = (l < 8);
    float4 xp_cur = make_float4(0.f, 0.f, 0.f, 0.f), xp_next = xp_cur;
    if (fin) xp_cur = *(const float4*)&P[(size_t)tok_lds[0] * 256 + row0];

    for (int t = 0; t < len; ++t) {
        if (fin && t + 1 < len)
            xp_next = *(const float4*)&P[(size_t)tok_lds[t + 1] * 256 + row0];

        // ---- FMA phase: 8 broadcast b128 reads (bank-rotated groups), 128 FMAs ----
        const float* hc = &hbuf[t & 1][cgrp * GSTRIDE];
        float a0 = 0.f, a1 = 0.f, a2 = 0.f, a3 = 0.f;
        #pragma unroll
        for (int m = 0; m < 8; ++m) {
            float4 h4 = *(const float4*)(hc + 4 * m);
            a0 = fmaf(wv[0][m].x, h4.x, a0); a0 = fmaf(wv[0][m].y, h4.y, a0);
            a0 = fmaf(wv[0][m].z, h4.z, a0); a0 = fmaf(wv[0][m].w, h4.w, a0);
            a1 = fmaf(wv[1][m].x, h4.x, a1); a1 = fmaf(wv[1][m].y, h4.y, a1);
            a1 = fmaf(wv[1][m].z, h4.z, a1); a1 = fmaf(wv[1][m].w, h4.w, a1);
            a2 = fmaf(wv[2][m].x, h4.x, a2); a2 = fmaf(wv[2][m].y, h4.y, a2);
            a2 = fmaf(wv[2][m].z, h4.z, a2); a2 = fmaf(wv[2][m].w, h4.w, a2);
            a3 = fmaf(wv[3][m].x, h4.x, a3); a3 = fmaf(wv[3][m].y, h4.y, a3);
            a3 = fmaf(wv[3][m].z, h4.z, a3); a3 = fmaf(wv[3][m].w, h4.w, a3);
        }

        // ---- in-wave butterfly over col groups (lane bits 3,4,5) ----
        a0 += __shfl_xor(a0, 8, 64);  a1 += __shfl_xor(a1, 8, 64);
        a2 += __shfl_xor(a2, 8, 64);  a3 += __shfl_xor(a3, 8, 64);
        a0 += __shfl_xor(a0, 16, 64); a1 += __shfl_xor(a1, 16, 64);
        a2 += __shfl_xor(a2, 16, 64); a3 += __shfl_xor(a3, 16, 64);
        a0 += __shfl_xor(a0, 32, 64); a1 += __shfl_xor(a1, 32, 64);
        a2 += __shfl_xor(a2, 32, 64); a3 += __shfl_xor(a3, 32, 64);

        // ---- finalize: lanes 0..7 own rows row0..row0+3 ----
        if (fin) {
            float4 hn;
            hn.x = tanh_fast(xp_cur.x + a0);
            hn.y = tanh_fast(xp_cur.y + a1);
            hn.z = tanh_fast(xp_cur.z + a2);
            hn.w = tanh_fast(xp_cur.w + a3);
            *(float4*)&hbuf[(t + 1) & 1][w * GSTRIDE + 4 * l] = hn;
            xp_cur = xp_next;
        }
        __syncthreads();   // single barrier per step (double-buffered h)
    }

    // ---- classifier head (h stored padded: idx -> idx + (idx>>5)*4) ----
    const float* hf = hbuf[len & 1];
    if (tid < 128) {
        int c = tid >> 6, l2 = tid & 63;
        float sacc = 0.f;
        #pragma unroll
        for (int q = 0; q < 4; ++q) {
            int idx = q * 64 + l2;
            sacc += Wcls[c * 256 + idx] * hf[idx + ((idx >> 5) << 2)];
        }
        #pragma unroll
        for (int off = 32; off > 0; off >>= 1)
            sacc += __shfl_down(sacc, off, 64);
        if (l2 == 0) out[b * 2 + c] = sacc + bcls[c];
    }
}

// ------------------------------- launcher ------------------------------------
extern "C" void kernel_launch(void* const* d_in, const int* in_sizes, int n_in,
                              void* d_out, int out_size, void* d_ws, size_t ws_size,
                              hipStream_t stream) {
    const int*   reviews = (const int*)d_in[0];
    const int*   lengths = (const int*)d_in[1];
    const float* emb     = (const float*)d_in[2];
    const float* W_ih    = (const float*)d_in[3];
    const float* W_hh    = (const float*)d_in[4];
    const float* W_cls   = (const float*)d_in[5];
    const float* b_cls   = (const float*)d_in[6];
    float* out = (float*)d_out;

    float* WT = (float*)d_ws;
    float* P  = WT + 256 * 256;

    k_transpose<<<256, 256, 0, stream>>>(W_ih, WT);
    k_project<<<(VOCAB + 31) / 32, 256, 0, stream>>>(emb, WT, P);
    k_rnn<<<BATCH, 512, 0, stream>>>(reviews, lengths, P, W_hh, W_cls, b_cls, out);
}

// Round 9
// 2020.157 us; speedup vs baseline: 1.1043x; 1.1043x over previous
//
#include <hip/hip_runtime.h>
#include <hip/hip_bf16.h>

#define VOCAB 50000
#define EDIM 256
#define HDIM 256
#define BATCH 64
#define SEQ 2048

// group stride in floats for padded h storage: 32 cols + 4 pad -> banks rotate by 4 per group
#define GSTRIDE 36

typedef __attribute__((ext_vector_type(2))) float v2f;

// ---------------- kernel 0: transpose W_ih (H x E) -> W_T (E x H) -------------
__global__ void k_transpose(const float* __restrict__ W, float* __restrict__ WT) {
    int idx = blockIdx.x * 256 + threadIdx.x;
    int e = idx >> 8;
    int i = idx & 255;
    WT[idx] = W[i * 256 + e];
}

// ---------------- kernel 1: P[v][i] = sum_e emb[v][e] * W_ih[i][e] ------------
__global__ __launch_bounds__(256) void k_project(const float* __restrict__ emb,
                                                 const float* __restrict__ WT,
                                                 float* __restrict__ P) {
    __shared__ float etile[32 * 256];
    const int v0 = blockIdx.x * 32;
    const int tid = threadIdx.x;

    #pragma unroll 4
    for (int k = 0; k < 32; ++k) {
        int v = v0 + k;
        etile[k * 256 + tid] = (v < VOCAB) ? emb[(size_t)v * 256 + tid] : 0.0f;
    }
    __syncthreads();

    float acc[32];
    #pragma unroll
    for (int k = 0; k < 32; ++k) acc[k] = 0.0f;

    for (int e0 = 0; e0 < 256; e0 += 4) {
        float w0 = WT[(size_t)(e0 + 0) * 256 + tid];
        float w1 = WT[(size_t)(e0 + 1) * 256 + tid];
        float w2 = WT[(size_t)(e0 + 2) * 256 + tid];
        float w3 = WT[(size_t)(e0 + 3) * 256 + tid];
        #pragma unroll
        for (int k = 0; k < 32; ++k) {
            float4 ev = *(const float4*)&etile[k * 256 + e0];
            acc[k] = fmaf(ev.x, w0, acc[k]);
            acc[k] = fmaf(ev.y, w1, acc[k]);
            acc[k] = fmaf(ev.z, w2, acc[k]);
            acc[k] = fmaf(ev.w, w3, acc[k]);
        }
    }
    #pragma unroll 4
    for (int k = 0; k < 32; ++k) {
        int v = v0 + k;
        if (v < VOCAB) P[(size_t)v * 256 + tid] = acc[k];
    }
}

// ---------------- kernel 2: recurrence -----------------------------------------
// 512 threads = 8 waves. Wave w owns output rows 32w..32w+31.
// Lane l: cgrp = l&7 (cols 32cgrp..+31), r8 = l>>3 (rows 32w+4*r8+{0..3}).
// Weights packed as float2 row-pairs -> v_pk_fma_f32 (64 pk-FMA/thread/step).
// 8-group col reduce over lane bits 0..2 via DPP row_shl:4/2/1 (VALU pipe; lane
// i <- lane i+N so the group sum lands on the LOW lane l&7==0. row_shr would
// land on l&7==7 — AMD's canonical DPP reduce ends v_readlane 63).
// NO ds_bpermute: round-7 showed __shfl_xor = LDS pipe = ~1000 cyc regression.
// Lanes l&7==0 finalize (xp + tanh) and ds_write_b128 h. Double-buffered h,
// ONE barrier per step.
__device__ __forceinline__ float tanh_fast(float x) {
    float ax = fabsf(x);
    float e  = __expf(-2.0f * ax);
    float r  = (1.0f - e) / (1.0f + e);
    return copysignf(r, x);
}

template <int CTRL>
__device__ __forceinline__ float dpp_shl_add(float a) {
    int t = __builtin_amdgcn_update_dpp(0, __float_as_int(a), CTRL, 0xf, 0xf, true);
    return a + __int_as_float(t);
}

__global__ __launch_bounds__(512, 2) void k_rnn(const int* __restrict__ tokens,
                                                const int* __restrict__ lengths,
                                                const float* __restrict__ P,
                                                const float* __restrict__ Whh,
                                                const float* __restrict__ Wcls,
                                                const float* __restrict__ bcls,
                                                float* __restrict__ out) {
    __shared__ float hbuf[2][8 * GSTRIDE];
    __shared__ int   tok_lds[SEQ];

    const int b   = blockIdx.x;
    const int tid = threadIdx.x;
    const int len = lengths[b];

    #pragma unroll
    for (int k = 0; k < 4; ++k)
        tok_lds[tid + k * 512] = tokens[b * SEQ + tid + k * 512];
    if (tid < 8 * GSTRIDE) hbuf[0][tid] = 0.0f;

    const int w    = tid >> 6;          // wave id 0..7 (row block)
    const int l    = tid & 63;          // lane
    const int cgrp = l & 7;             // col group (lane bits 0..2 -> DPP-reducible)
    const int r8   = l >> 3;            // row sub-block
    const int row0 = 32 * w + 4 * r8;   // this lane's 4 rows
    const int cb   = 32 * cgrp;         // col base

    // ---- weights -> packed row-pair registers ----
    v2f w01[8][4], w23[8][4];
    #pragma unroll
    for (int m = 0; m < 8; ++m) {
        float4 q0 = *(const float4*)(Whh + (size_t)(row0 + 0) * 256 + cb + 4 * m);
        float4 q1 = *(const float4*)(Whh + (size_t)(row0 + 1) * 256 + cb + 4 * m);
        float4 q2 = *(const float4*)(Whh + (size_t)(row0 + 2) * 256 + cb + 4 * m);
        float4 q3 = *(const float4*)(Whh + (size_t)(row0 + 3) * 256 + cb + 4 * m);
        w01[m][0] = (v2f){q0.x, q1.x}; w01[m][1] = (v2f){q0.y, q1.y};
        w01[m][2] = (v2f){q0.z, q1.z}; w01[m][3] = (v2f){q0.w, q1.w};
        w23[m][0] = (v2f){q2.x, q3.x}; w23[m][1] = (v2f){q2.y, q3.y};
        w23[m][2] = (v2f){q2.z, q3.z}; w23[m][3] = (v2f){q2.w, q3.w};
    }
    __syncthreads();

    const bool fin = (cgrp == 0);       // finalize lanes: 8 per wave (low lane of each group)
    float4 xp_cur = make_float4(0.f, 0.f, 0.f, 0.f), xp_next = xp_cur;
    if (fin) xp_cur = *(const float4*)&P[(size_t)tok_lds[0] * 256 + row0];

    for (int t = 0; t < len; ++t) {
        if (fin && t + 1 < len)
            xp_next = *(const float4*)&P[(size_t)tok_lds[t + 1] * 256 + row0];

        // ---- FMA phase: 8 bank-disjoint broadcast b128 reads, 64 pk-FMA ----
        const float* hc = &hbuf[t & 1][cgrp * GSTRIDE];
        v2f acc01 = (v2f){0.f, 0.f}, acc23 = (v2f){0.f, 0.f};
        #pragma unroll
        for (int m = 0; m < 8; ++m) {
            float4 h4 = *(const float4*)(hc + 4 * m);
            acc01 += w01[m][0] * (v2f){h4.x, h4.x};
            acc23 += w23[m][0] * (v2f){h4.x, h4.x};
            acc01 += w01[m][1] * (v2f){h4.y, h4.y};
            acc23 += w23[m][1] * (v2f){h4.y, h4.y};
            acc01 += w01[m][2] * (v2f){h4.z, h4.z};
            acc23 += w23[m][2] * (v2f){h4.z, h4.z};
            acc01 += w01[m][3] * (v2f){h4.w, h4.w};
            acc23 += w23[m][3] * (v2f){h4.w, h4.w};
        }

        // ---- 8-group reduce, low-lane accumulate: row_shl:4,2,1 (VALU DPP) ----
        float a0 = acc01.x, a1 = acc01.y, a2 = acc23.x, a3 = acc23.y;
        a0 = dpp_shl_add<0x104>(a0); a1 = dpp_shl_add<0x104>(a1);
        a2 = dpp_shl_add<0x104>(a2); a3 = dpp_shl_add<0x104>(a3);
        a0 = dpp_shl_add<0x102>(a0); a1 = dpp_shl_add<0x102>(a1);
        a2 = dpp_shl_add<0x102>(a2); a3 = dpp_shl_add<0x102>(a3);
        a0 = dpp_shl_add<0x101>(a0); a1 = dpp_shl_add<0x101>(a1);
        a2 = dpp_shl_add<0x101>(a2); a3 = dpp_shl_add<0x101>(a3);

        // ---- finalize: lanes cgrp==0 own rows row0..row0+3 ----
        if (fin) {
            float4 hn;
            hn.x = tanh_fast(xp_cur.x + a0);
            hn.y = tanh_fast(xp_cur.y + a1);
            hn.z = tanh_fast(xp_cur.z + a2);
            hn.w = tanh_fast(xp_cur.w + a3);
            *(float4*)&hbuf[(t + 1) & 1][w * GSTRIDE + 4 * r8] = hn;
            xp_cur = xp_next;
        }
        __syncthreads();   // single barrier per step (double-buffered h)
    }

    // ---- classifier head (h stored padded: idx -> idx + (idx>>5)*4) ----
    const float* hf = hbuf[len & 1];
    if (tid < 128) {
        int c = tid >> 6, l2 = tid & 63;
        float sacc = 0.f;
        #pragma unroll
        for (int q = 0; q < 4; ++q) {
            int idx = q * 64 + l2;
            sacc += Wcls[c * 256 + idx] * hf[idx + ((idx >> 5) << 2)];
        }
        #pragma unroll
        for (int off = 32; off > 0; off >>= 1)
            sacc += __shfl_down(sacc, off, 64);
        if (l2 == 0) out[b * 2 + c] = sacc + bcls[c];
    }
}

// ------------------------------- launcher ------------------------------------
extern "C" void kernel_launch(void* const* d_in, const int* in_sizes, int n_in,
                              void* d_out, int out_size, void* d_ws, size_t ws_size,
                              hipStream_t stream) {
    const int*   reviews = (const int*)d_in[0];
    const int*   lengths = (const int*)d_in[1];
    const float* emb     = (const float*)d_in[2];
    const float* W_ih    = (const float*)d_in[3];
    const float* W_hh    = (const float*)d_in[4];
    const float* W_cls   = (const float*)d_in[5];
    const float* b_cls   = (const float*)d_in[6];
    float* out = (float*)d_out;

    float* WT = (float*)d_ws;
    float* P  = WT + 256 * 256;

    k_transpose<<<256, 256, 0, stream>>>(W_ih, WT);
    k_project<<<(VOCAB + 31) / 32, 256, 0, stream>>>(emb, WT, P);
    k_rnn<<<BATCH, 512, 0, stream>>>(reviews, lengths, P, W_hh, W_cls, b_cls, out);
}